// Round 1
// baseline (482.776 us; speedup 1.0000x reference)
//
#include <hip/hip_runtime.h>
#include <hip/hip_bf16.h>

// Problem constants (reference): B=64, N=256, S=16, HID=32, HEADS=8
#define BB 64
#define NN 256
#define SS 16
#define HH 32
#define KK 8      // heads
#define NROWPAIRS (BB*NN)          // 16384 (b,n) pairs
#define STATS_BLOCKS 2048

// ---- workspace layout (bytes) ----
// 0    : int mode        (0=int32 mask, 1=byte mask, 2=float mask)
// 4    : int countRows   (# valid (b,n) pairs)
// 64   : uchar valid[16384]
// 16448: float sx[16]
// 16512: float sx2[16]
// 16576: float b1c[32]
// 16704: float W1c[512]

// ---------------------------------------------------------------------------
// Kernel A: single block. Detect mask dtype, build valid[], count valid rows,
// zero the float accumulators (ws is poisoned 0xAA before every launch).
// ---------------------------------------------------------------------------
__global__ void prep_kernel(const void* __restrict__ mask_raw,
                            int* __restrict__ mode_out,
                            int* __restrict__ count_out,
                            unsigned char* __restrict__ valid,
                            float* __restrict__ sx,
                            float* __restrict__ sx2) {
    int tid = threadIdx.x;
    if (tid < 16) { sx[tid] = 0.0f; sx2[tid] = 0.0f; }

    __shared__ int s_flags[2];   // [0]=float pattern seen, [1]=bool pattern seen
    __shared__ int s_mode;
    __shared__ int s_count;
    if (tid < 2) s_flags[tid] = 0;
    if (tid == 0) s_count = 0;
    __syncthreads();

    // Scan first 16384 bytes as 4096 words (in-bounds for all 3 layouts).
    const unsigned int* w = (const unsigned int*)mask_raw;
    int f_float = 0, f_bool = 0;
    for (int i = tid; i < 4096; i += 1024) {
        unsigned int v = w[i];
        if (v == 0x3F800000u) f_float = 1;
        // a byte value of exactly 1 in a non-LSB position can only be
        // packed bool bytes (int 0/1 and float 0.0/1.0 never produce it)
        if (((v >> 8) & 0xFFu) == 1u || ((v >> 16) & 0xFFu) == 1u ||
            ((v >> 24) & 0xFFu) == 1u) f_bool = 1;
    }
    if (f_float) atomicOr(&s_flags[0], 1);
    if (f_bool)  atomicOr(&s_flags[1], 1);
    __syncthreads();
    if (tid == 0) {
        int mode = s_flags[1] ? 1 : (s_flags[0] ? 2 : 0);
        s_mode = mode;
        *mode_out = mode;
    }
    __syncthreads();
    int mode = s_mode;

    int localc = 0;
    for (int i = tid; i < NROWPAIRS; i += 1024) {
        int masked;
        if (mode == 1)      masked = ((const unsigned char*)mask_raw)[i] != 0;
        else if (mode == 2) masked = ((const float*)mask_raw)[i] != 0.0f;
        else                masked = ((const int*)mask_raw)[i] != 0;
        unsigned char v = (unsigned char)(masked ? 0 : 1);  // valid = !mask
        valid[i] = v;
        localc += v;
    }
    atomicAdd(&s_count, localc);
    __syncthreads();
    if (tid == 0) *count_out = s_count;
}

// ---------------------------------------------------------------------------
// Kernel B: masked sum / sum-of-squares per channel s.
// One (b,n) pair = 16KB chunk (256 m-rows x 16 floats) = 1024 float4.
// Block of 256 threads handles 8 chunks; skip is block-uniform.
// Thread's float4 always covers s = 4*(tid%4)..+3.
// ---------------------------------------------------------------------------
__global__ __launch_bounds__(256) void stats_kernel(
        const float* __restrict__ stacks,
        const unsigned char* __restrict__ valid,
        float* __restrict__ sx, float* __restrict__ sx2) {
    int tid = threadIdx.x;
    float4 s1 = make_float4(0.f, 0.f, 0.f, 0.f);
    float4 s2 = make_float4(0.f, 0.f, 0.f, 0.f);

    for (int k = 0; k < NROWPAIRS / STATS_BLOCKS; ++k) {
        int chunk = blockIdx.x + k * STATS_BLOCKS;
        if (!valid[chunk]) continue;               // block-uniform branch
        const float4* p = (const float4*)stacks + (size_t)chunk * 1024;
        #pragma unroll
        for (int it = 0; it < 4; ++it) {
            float4 v = p[tid + it * 256];
            s1.x += v.x; s1.y += v.y; s1.z += v.z; s1.w += v.w;
            s2.x += v.x * v.x; s2.y += v.y * v.y;
            s2.z += v.z * v.z; s2.w += v.w * v.w;
        }
    }

    __shared__ float lds[8 * 256];   // [comp][tid]
    lds[0 * 256 + tid] = s1.x; lds[1 * 256 + tid] = s1.y;
    lds[2 * 256 + tid] = s1.z; lds[3 * 256 + tid] = s1.w;
    lds[4 * 256 + tid] = s2.x; lds[5 * 256 + tid] = s2.y;
    lds[6 * 256 + tid] = s2.z; lds[7 * 256 + tid] = s2.w;
    __syncthreads();

    if (tid < 32) {
        int kind = tid >> 4;          // 0 = sum, 1 = sum sq
        int s = tid & 15;
        int g = s >> 2, c = (s & 3) + kind * 4;
        float tot = 0.f;
        for (int i = 0; i < 64; ++i) tot += lds[c * 256 + (g + i * 4)];
        atomicAdd(kind ? &sx2[s] : &sx[s], tot);
    }
}

// ---------------------------------------------------------------------------
// Kernel C: fold BN into layer 1.  scale = gamma/sqrt(var+eps),
// shift = beta - mean*scale;  W1c = scale (.) W1;  b1c = shift @ W1 + b1.
// ---------------------------------------------------------------------------
__global__ void weights_kernel(const float* __restrict__ gamma,
                               const float* __restrict__ beta,
                               const float* __restrict__ W1,
                               const float* __restrict__ b1,
                               const float* __restrict__ sx,
                               const float* __restrict__ sx2,
                               const int* __restrict__ count_rows,
                               float* __restrict__ W1c,
                               float* __restrict__ b1c) {
    __shared__ float s_scale[SS], s_shift[SS];
    int tid = threadIdx.x;
    if (tid < SS) {
        float cnt = (float)(*count_rows) * (float)NN;
        if (cnt < 1.0f) cnt = 1.0f;
        float mean = sx[tid] / cnt;
        float var  = sx2[tid] / cnt - mean * mean;
        float sc   = gamma[tid] / sqrtf(var + 1e-5f);
        s_scale[tid] = sc;
        s_shift[tid] = beta[tid] - mean * sc;
    }
    __syncthreads();
    if (tid < SS * HH) W1c[tid] = s_scale[tid >> 5] * W1[tid];
    if (tid < HH) {
        float acc = b1[tid];
        #pragma unroll
        for (int s = 0; s < SS; ++s) acc += s_shift[s] * W1[s * HH + tid];
        b1c[tid] = acc;
    }
}

// ---------------------------------------------------------------------------
// Kernel D: per-row fused MLP. Block = one (b,n) pair (mask branch is
// block-uniform); thread = one m row. 16 floats in, 8 floats out.
// ---------------------------------------------------------------------------
__global__ __launch_bounds__(256) void mlp_kernel(
        const float* __restrict__ stacks,
        const unsigned char* __restrict__ valid,
        const float* __restrict__ W1c,
        const float* __restrict__ b1c,
        const float* __restrict__ W2,
        const float* __restrict__ b2,
        float* __restrict__ out) {
    int bid = blockIdx.x;
    int tid = threadIdx.x;
    size_t row = (size_t)bid * NN + tid;
    float4* outp = (float4*)out + row * 2;

    if (!valid[bid]) {
        float4 z = make_float4(0.f, 0.f, 0.f, 0.f);
        outp[0] = z; outp[1] = z;
        return;
    }

    const float4* xp = (const float4*)stacks + row * 4;
    float4 x0 = xp[0], x1 = xp[1], x2 = xp[2], x3 = xp[3];
    float x[SS] = { x0.x, x0.y, x0.z, x0.w,  x1.x, x1.y, x1.z, x1.w,
                    x2.x, x2.y, x2.z, x2.w,  x3.x, x3.y, x3.z, x3.w };

    float h[HH];
    #pragma unroll
    for (int j = 0; j < HH; ++j) h[j] = b1c[j];
    #pragma unroll
    for (int k = 0; k < SS; ++k) {
        float xk = x[k];
        #pragma unroll
        for (int j = 0; j < HH; ++j) h[j] = fmaf(xk, W1c[k * HH + j], h[j]);
    }
    #pragma unroll
    for (int j = 0; j < HH; ++j) h[j] = fmaxf(h[j], 0.0f);

    float y[KK];
    #pragma unroll
    for (int i = 0; i < KK; ++i) y[i] = b2[i];
    #pragma unroll
    for (int j = 0; j < HH; ++j) {
        float hj = h[j];
        #pragma unroll
        for (int i = 0; i < KK; ++i) y[i] = fmaf(hj, W2[j * KK + i], y[i]);
    }

    outp[0] = make_float4(y[0], y[1], y[2], y[3]);
    outp[1] = make_float4(y[4], y[5], y[6], y[7]);
}

extern "C" void kernel_launch(void* const* d_in, const int* in_sizes, int n_in,
                              void* d_out, int out_size, void* d_ws, size_t ws_size,
                              hipStream_t stream) {
    const float* stacks = (const float*)d_in[0];
    const void*  mask   = d_in[1];
    const float* gamma  = (const float*)d_in[2];
    const float* beta   = (const float*)d_in[3];
    const float* W1     = (const float*)d_in[4];
    const float* b1     = (const float*)d_in[5];
    const float* W2     = (const float*)d_in[6];
    const float* b2     = (const float*)d_in[7];
    float* out = (float*)d_out;

    char* ws = (char*)d_ws;
    int*           mode      = (int*)(ws + 0);
    int*           countRows = (int*)(ws + 4);
    unsigned char* valid     = (unsigned char*)(ws + 64);
    float*         sx        = (float*)(ws + 16448);
    float*         sx2       = (float*)(ws + 16512);
    float*         b1c       = (float*)(ws + 16576);
    float*         W1c       = (float*)(ws + 16704);

    prep_kernel<<<1, 1024, 0, stream>>>(mask, mode, countRows, valid, sx, sx2);
    stats_kernel<<<STATS_BLOCKS, 256, 0, stream>>>(stacks, valid, sx, sx2);
    weights_kernel<<<1, 512, 0, stream>>>(gamma, beta, W1, b1, sx, sx2,
                                          countRows, W1c, b1c);
    mlp_kernel<<<NROWPAIRS, 256, 0, stream>>>(stacks, valid, W1c, b1c, W2, b2, out);
}